// Round 1
// baseline (216.487 us; speedup 1.0000x reference)
//
#include <hip/hip_runtime.h>
#include <hip/hip_bf16.h>
#include <stdint.h>

#define NDIM 4096
#define BM 128
#define BN 128
#define BK 64            // 8 chunks of 8 bf16 (16B vaults) per row
#define SPLIT_D 16       // tiles with d >= SPLIT_D are K-split across 2 blocks

typedef __attribute__((ext_vector_type(8))) short bf16x8;
typedef __attribute__((ext_vector_type(8))) unsigned short u16x8;
typedef __attribute__((ext_vector_type(4))) float f32x4;   // native vec: ok for nontemporal builtins

__device__ __forceinline__ unsigned short f2bf(float f) {
    union { float f; uint32_t u; } v; v.f = f;
    uint32_t u = v.u;
    u += 0x7FFFu + ((u >> 16) & 1u);   // round-to-nearest-even
    return (unsigned short)(u >> 16);
}

// --- Fused prep kernel ---
// blocks [0,2048):    A (fp32) -> triu-masked bf16 row-major (8192 elems/block)
// blocks [2048,4096): B -> triu-masked bf16 transposed Bt[c][k] (64k x 128c per block)
__global__ __launch_bounds__(256) void prep_kernel(const float* __restrict__ A,
                                                   const float* __restrict__ B,
                                                   unsigned short* __restrict__ Abf,
                                                   unsigned short* __restrict__ Bt) {
    __shared__ float lds[32 * 65];
    const int b   = blockIdx.x;
    const int tid = threadIdx.x;

    if (b < 2048) {
        #pragma unroll
        for (int it = 0; it < 4; ++it) {
            int idx = b * 8192 + it * 2048 + tid * 8;
            int row = idx >> 12;
            int col = idx & 4095;
            f32x4 v0 = __builtin_nontemporal_load((const f32x4*)(A + idx));
            f32x4 v1 = __builtin_nontemporal_load((const f32x4*)(A + idx + 4));
            u16x8 o;
            o[0] = (col + 0 >= row) ? f2bf(v0.x) : (unsigned short)0;
            o[1] = (col + 1 >= row) ? f2bf(v0.y) : (unsigned short)0;
            o[2] = (col + 2 >= row) ? f2bf(v0.z) : (unsigned short)0;
            o[3] = (col + 3 >= row) ? f2bf(v0.w) : (unsigned short)0;
            o[4] = (col + 4 >= row) ? f2bf(v1.x) : (unsigned short)0;
            o[5] = (col + 5 >= row) ? f2bf(v1.y) : (unsigned short)0;
            o[6] = (col + 6 >= row) ? f2bf(v1.z) : (unsigned short)0;
            o[7] = (col + 7 >= row) ? f2bf(v1.w) : (unsigned short)0;
            *(u16x8*)(Abf + idx) = o;
        }
    } else {
        // B transpose+convert: block covers 64 k-rows x 128 c-cols as 4 sub-tiles
        int tb = b - 2048;
        int k0 = (tb >> 5) * 64;           // 64 k-groups
        int c0 = (tb & 31) * 128;          // 32 c-groups
        #pragma unroll
        for (int s = 0; s < 4; ++s) {
            int c0s = c0 + s * 32;
            #pragma unroll
            for (int p = 0; p < 2; ++p) {
                int kr = p * 32 + (tid >> 3);
                int cc = (tid & 7) * 4;
                f32x4 v = __builtin_nontemporal_load(
                    (const f32x4*)(B + (size_t)(k0 + kr) * NDIM + c0s + cc));
                lds[(cc + 0) * 65 + kr] = v.x;
                lds[(cc + 1) * 65 + kr] = v.y;
                lds[(cc + 2) * 65 + kr] = v.z;
                lds[(cc + 3) * 65 + kr] = v.w;
            }
            __syncthreads();
            int c  = tid >> 3;
            int ks = (tid & 7) * 8;
            u16x8 o;
            #pragma unroll
            for (int j = 0; j < 8; ++j) {
                float f = lds[c * 65 + ks + j];
                o[j] = (k0 + ks + j <= c0s + c) ? f2bf(f) : (unsigned short)0;
            }
            *(u16x8*)(Bt + (size_t)(c0s + c) * NDIM + k0 + ks) = o;
            __syncthreads();
        }
    }
}

// --- Triangular bf16 MFMA GEMM, K-split for balance ---
// Upper tiles enumerated d = bj-bi descending. Tiles with d >= SPLIT_D get TWO
// blocks, each doing (d+1) K-steps; khalf 1 stores to the true tile, khalf 0
// stores its partial to the (otherwise zero) mirror tile (bj,bi). treduce_kernel
// merges mirror into true and re-zeroes the mirror. Max per-block K-steps: 32.
// Atomic-free, no extra workspace, FETCH unchanged (halves stage disjoint K).
__global__ __launch_bounds__(256, 2) void trigemm_kernel(
        const unsigned short* __restrict__ Abf,
        const unsigned short* __restrict__ Bt,
        float* __restrict__ C) {
    int rem = blockIdx.x, d = 31, g = 2;           // g(31) = (32-31)*2
    while (rem >= g) { rem -= g; --d; g = (32 - d) * (d >= SPLIT_D ? 2 : 1); }
    int bi, khalf, nsteps;
    if (d >= SPLIT_D) { bi = rem >> 1; khalf = rem & 1; nsteps = d + 1; }
    else              { bi = rem;      khalf = 0;       nsteps = 2 * (d + 1); }
    const int bj = bi + d;

    __shared__ unsigned short As[BM * BK];   // 16 KB
    __shared__ unsigned short Bs[BN * BK];   // 16 KB

    const int tid  = threadIdx.x;
    const int wave = tid >> 6, lane = tid & 63;
    const int wm = wave >> 1, wn = wave & 1;
    const int m_l = lane & 15, kh = lane >> 4;
    const int ml7 = m_l & 7;

    f32x4 acc[4][4] = {};

    const int i0 = bi * BM, j0 = bj * BN;
    const int k_start = i0 + khalf * (d + 1) * BK;

    const unsigned short* Ar = Abf + (size_t)i0 * NDIM;
    const unsigned short* Br = Bt  + (size_t)j0 * NDIM;

    // staging map: pass p covers row r0+32p, chunk kc (16B); xor depends only on r0&7
    const int r0 = tid >> 3, kc = tid & 7;
    const int woff = r0 * BK + ((kc ^ (r0 & 7)) * 8);       // LDS short idx, + p*2048
    const size_t g0 = (size_t)r0 * NDIM + kc * 8;           // + p*32*NDIM + koff

    u16x8 a0_0, a0_1, a0_2, a0_3, b0_0, b0_1, b0_2, b0_3;
    u16x8 a1_0, a1_1, a1_2, a1_3, b1_0, b1_1, b1_2, b1_3;

#define LOAD_STAGE(AN, BN_, koff) do {                                          \
        const size_t _g = g0 + (size_t)(koff);                                  \
        AN##_0 = *(const u16x8*)(Ar + _g);                                      \
        AN##_1 = *(const u16x8*)(Ar + _g + (size_t)32 * NDIM);                  \
        AN##_2 = *(const u16x8*)(Ar + _g + (size_t)64 * NDIM);                  \
        AN##_3 = *(const u16x8*)(Ar + _g + (size_t)96 * NDIM);                  \
        BN_##_0 = *(const u16x8*)(Br + _g);                                     \
        BN_##_1 = *(const u16x8*)(Br + _g + (size_t)32 * NDIM);                 \
        BN_##_2 = *(const u16x8*)(Br + _g + (size_t)64 * NDIM);                 \
        BN_##_3 = *(const u16x8*)(Br + _g + (size_t)96 * NDIM);                 \
    } while (0)

#define WRITE_STAGE(AN, BN_) do {                                               \
        *(u16x8*)&As[woff         ] = AN##_0;                                   \
        *(u16x8*)&As[woff + 1*2048] = AN##_1;                                   \
        *(u16x8*)&As[woff + 2*2048] = AN##_2;                                   \
        *(u16x8*)&As[woff + 3*2048] = AN##_3;                                   \
        *(u16x8*)&Bs[woff         ] = BN_##_0;                                  \
        *(u16x8*)&Bs[woff + 1*2048] = BN_##_1;                                  \
        *(u16x8*)&Bs[woff + 2*2048] = BN_##_2;                                  \
        *(u16x8*)&Bs[woff + 3*2048] = BN_##_3;                                  \
    } while (0)

#define COMPUTE() do {                                                          \
        _Pragma("unroll")                                                       \
        for (int s = 0; s < 2; ++s) {                                           \
            const int xk = ((s * 4 + kh) ^ ml7) * 8;                            \
            bf16x8 bfr[4], afr[4];                                              \
            _Pragma("unroll")                                                   \
            for (int nt = 0; nt < 4; ++nt)                                      \
                bfr[nt] = *(const bf16x8*)&Bs[(wn*64 + nt*16 + m_l)*BK + xk];   \
            _Pragma("unroll")                                                   \
            for (int mt = 0; mt < 4; ++mt)                                      \
                afr[mt] = *(const bf16x8*)&As[(wm*64 + mt*16 + m_l)*BK + xk];   \
            _Pragma("unroll")                                                   \
            for (int mt = 0; mt < 4; ++mt)                                      \
                _Pragma("unroll")                                               \
                for (int nt = 0; nt < 4; ++nt)                                  \
                    acc[mt][nt] = __builtin_amdgcn_mfma_f32_16x16x32_bf16(      \
                        afr[mt], bfr[nt], acc[mt][nt], 0, 0, 0);                \
        }                                                                       \
    } while (0)

    LOAD_STAGE(a0, b0, k_start);
    if (nsteps > 1) LOAD_STAGE(a1, b1, k_start + BK);

    int it = 0;
    for (; it + 2 <= nsteps; it += 2) {
        WRITE_STAGE(a0, b0);                 // vmcnt wait: loads issued 2 iters ago
        if (it + 2 < nsteps) LOAD_STAGE(a0, b0, k_start + (it + 2) * BK);
        __syncthreads();
        COMPUTE();
        __syncthreads();
        WRITE_STAGE(a1, b1);
        if (it + 3 < nsteps) LOAD_STAGE(a1, b1, k_start + (it + 3) * BK);
        __syncthreads();
        COMPUTE();
        __syncthreads();
    }
    if (it < nsteps) {                       // odd K-step tail (split halves)
        WRITE_STAGE(a0, b0);
        __syncthreads();
        COMPUTE();
        __syncthreads();
    }
#undef LOAD_STAGE
#undef WRITE_STAGE
#undef COMPUTE

    // Epilogue: C/D layout col=lane&15, row=(lane>>4)*4+reg (m89/m91-verified).
    // Inputs triu-masked -> below-diagonal accs exactly 0; plain stores.
    // Split khalf 0 targets the mirror tile (bj,bi) as a partial-sum buffer.
    const bool to_mirror = (d >= SPLIT_D) && (khalf == 0);
    float* Cbase = to_mirror ? (C + (size_t)j0 * NDIM + i0)
                             : (C + (size_t)i0 * NDIM + j0);
    #pragma unroll
    for (int mt = 0; mt < 4; ++mt) {
        #pragma unroll
        for (int nt = 0; nt < 4; ++nt) {
            #pragma unroll
            for (int r = 0; r < 4; ++r) {
                int row = wm * 64 + mt * 16 + kh * 4 + r;
                int col = wn * 64 + nt * 16 + m_l;
                __builtin_nontemporal_store(acc[mt][nt][r],
                                            Cbase + (size_t)row * NDIM + col);
            }
        }
    }
    // Mirror lower tile (bj,bi) zero-fill, ONLY for unsplit tiles
    // (split tiles' mirrors hold partials; treduce zeroes them).
    if (bi != bj && d < SPLIT_D) {
        float* Z = C + (size_t)j0 * NDIM + i0;
        f32x4 z = {0.f, 0.f, 0.f, 0.f};
        #pragma unroll
        for (int t = 0; t < 16; ++t) {
            int off = (t * 256 + tid) * 4;
            int rr = off >> 7, cc = off & 127;
            __builtin_nontemporal_store(z, (f32x4*)(Z + (size_t)rr * NDIM + cc));
        }
    }
}

// --- Merge split-tile partials: C[true] += C[mirror]; C[mirror] = 0 ---
// 136 split tiles (d >= SPLIT_D), 4 blocks per tile (quarter-tile each).
__global__ __launch_bounds__(256) void treduce_kernel(float* __restrict__ C) {
    const int b = blockIdx.x >> 2, q = blockIdx.x & 3;
    int rem = b, d = 31;
    while (rem >= 32 - d) { rem -= 32 - d; --d; }   // d runs 31..SPLIT_D
    const int bi = rem, bj = bi + d;
    const int i0 = bi * BM, j0 = bj * BN;
    float* T  = C + (size_t)i0 * NDIM + j0;   // true tile
    float* Mr = C + (size_t)j0 * NDIM + i0;   // mirror (partial buffer)
    const int tid = threadIdx.x;
    const f32x4 z = {0.f, 0.f, 0.f, 0.f};
    #pragma unroll
    for (int t = 0; t < 4; ++t) {
        int off = ((q * 4 + t) * 256 + tid) * 4;
        int rr = off >> 7, cc = off & 127;
        f32x4 p = __builtin_nontemporal_load((const f32x4*)(Mr + (size_t)rr * NDIM + cc));
        f32x4 v = *(const f32x4*)(T + (size_t)rr * NDIM + cc);
        v = v + p;
        __builtin_nontemporal_store(v, (f32x4*)(T + (size_t)rr * NDIM + cc));
        __builtin_nontemporal_store(z, (f32x4*)(Mr + (size_t)rr * NDIM + cc));
    }
}

extern "C" void kernel_launch(void* const* d_in, const int* in_sizes, int n_in,
                              void* d_out, int out_size, void* d_ws, size_t ws_size,
                              hipStream_t stream) {
    const float* A = (const float*)d_in[0];
    const float* B = (const float*)d_in[1];
    float* C = (float*)d_out;

    unsigned short* Abf = (unsigned short*)d_ws;                   // 32 MB
    unsigned short* Bt  = Abf + (size_t)NDIM * NDIM;               // 32 MB

    prep_kernel<<<4096, 256, 0, stream>>>(A, B, Abf, Bt);
    // blocks: sum_{d>=16} 2*(32-d) + sum_{d<16} (32-d) = 272 + 392 = 664
    trigemm_kernel<<<664, 256, 0, stream>>>(Abf, Bt, C);
    treduce_kernel<<<136 * 4, 256, 0, stream>>>(C);
}